// Round 11
// baseline (250.070 us; speedup 1.0000x reference)
//
#include <hip/hip_runtime.h>
#include <math.h>

#define Bn 4
#define Cn 32
#define Dn 64
#define Hn 64
#define Wn 64
#define HW (Hn * Wn)
#define DHW (Dn * Hn * Wn)      /* 262144 */
#define TOT (Bn * Cn * DHW)     /* 33554432 */
#define NCHUNK 256              /* spatial chunks per batch in reduce */

typedef float f4 __attribute__((ext_vector_type(4)));

// ============================================================
// Kernel 1: fused reductions (atomic-free, fence-free).
// 1024 blocks (4/CU); channel loop batched 8-wide for load ILP.
// ============================================================
__global__ __launch_bounds__(256, 4) void reduce_kernel(
    const float* __restrict__ x,
    float* __restrict__ s_avg, float* __restrict__ s_max,
    float* __restrict__ part_sum, float* __restrict__ part_max) {
    const int b = blockIdx.x / NCHUNK;
    const int chunk = blockIdx.x % NCHUNK;
    const int base = chunk * 1024 + threadIdx.x * 4;
    const int lane = threadIdx.x & 63;
    const int wid = threadIdx.x >> 6;

    f4 ssum = {0.f, 0.f, 0.f, 0.f};
    f4 smax = {-INFINITY, -INFINITY, -INFINITY, -INFINITY};
    float tsum[Cn], tmax[Cn];

    const float* xp = x + (size_t)b * Cn * DHW + base;
#pragma unroll
    for (int g = 0; g < Cn / 8; ++g) {
        f4 v[8];
#pragma unroll
        for (int j = 0; j < 8; ++j)
            v[j] = *reinterpret_cast<const f4*>(xp + (size_t)(g * 8 + j) * DHW);
#pragma unroll
        for (int j = 0; j < 8; ++j) {
            const int c = g * 8 + j;
            ssum += v[j];
            smax.x = fmaxf(smax.x, v[j].x); smax.y = fmaxf(smax.y, v[j].y);
            smax.z = fmaxf(smax.z, v[j].z); smax.w = fmaxf(smax.w, v[j].w);
            tsum[c] = (v[j].x + v[j].y) + (v[j].z + v[j].w);
            tmax[c] = fmaxf(fmaxf(v[j].x, v[j].y), fmaxf(v[j].z, v[j].w));
        }
    }

    *reinterpret_cast<f4*>(s_avg + (size_t)b * DHW + base) = ssum * (1.f / Cn);
    *reinterpret_cast<f4*>(s_max + (size_t)b * DHW + base) = smax;

    __shared__ float redS[4][Cn];
    __shared__ float redM[4][Cn];
#pragma unroll
    for (int c = 0; c < Cn; ++c) {
        float ps = tsum[c], pm = tmax[c];
#pragma unroll
        for (int off = 32; off; off >>= 1) {
            ps += __shfl_xor(ps, off);
            pm = fmaxf(pm, __shfl_xor(pm, off));
        }
        if (lane == 0) { redS[wid][c] = ps; redM[wid][c] = pm; }
    }
    __syncthreads();
    if (threadIdx.x < Cn) {
        const int c = threadIdx.x;
        float s = (redS[0][c] + redS[1][c]) + (redS[2][c] + redS[3][c]);
        float m = fmaxf(fmaxf(redM[0][c], redM[1][c]),
                        fmaxf(redM[2][c], redM[3][c]));
        part_sum[(b * Cn + c) * NCHUNK + chunk] = s;
        part_max[(b * Cn + c) * NCHUNK + chunk] = m;
    }
}

// ============================================================
// Kernel 2: partial-reduce + channel-attention MLP. 1 block, 256 threads.
// ============================================================
__global__ __launch_bounds__(256) void ca_kernel(
    const float* __restrict__ part_sum, const float* __restrict__ part_max,
    const float* __restrict__ fc1_w, const float* __restrict__ fc1_b,
    const float* __restrict__ fc2_w, const float* __restrict__ fc2_b,
    float* __restrict__ ca) {
    __shared__ float inpAll[Bn][64];
    __shared__ float h[128];
    const int t = threadIdx.x;
    {
        const int which = t >> 7;        // 0: sum, 1: max
        const int b = (t >> 5) & 3;
        const int c = t & 31;
        const f4* p4 = reinterpret_cast<const f4*>(
            (which ? part_max : part_sum) + (b * Cn + c) * NCHUNK);
        if (which == 0) {
            float acc = 0.f;
#pragma unroll
            for (int i = 0; i < NCHUNK / 4; ++i) {
                f4 v = p4[i];
                acc += (v.x + v.y) + (v.z + v.w);
            }
            inpAll[b][c] = acc * (1.f / DHW);
        } else {
            float m = -INFINITY;
#pragma unroll
            for (int i = 0; i < NCHUNK / 4; ++i) {
                f4 v = p4[i];
                m = fmaxf(m, fmaxf(fmaxf(v.x, v.y), fmaxf(v.z, v.w)));
            }
            inpAll[b][Cn + c] = m;
        }
    }
    __syncthreads();
#pragma unroll 1
    for (int b = 0; b < Bn; ++b) {
        if (t < 128) {
            float acc = fc1_b[t];
#pragma unroll
            for (int k = 0; k < 64; ++k) acc += fc1_w[t * 64 + k] * inpAll[b][k];
            h[t] = fmaxf(acc, 0.f);
        }
        __syncthreads();
        if (t < Cn) {
            float a2 = fc2_b[t];
#pragma unroll
            for (int k = 0; k < 128; ++k) a2 += fc2_w[t * 128 + k] * h[k];
            ca[b * Cn + t] = 1.f / (1.f + expf(-a2));
        }
        __syncthreads();
    }
}

// ============================================================
// Kernel 3: conv + epilogue.
//  R10 lesson: per-iteration WEIGHT s_loads mixed with ds_reads force
//  lgkmcnt(0) drains (SMEM returns OOO vs DS). Fix: weights pre-staged in
//  LDS, reordered [ic][kh][kw][kd*4+oc] -> 7 uniform ds_read_b128 per
//  group (broadcast, counted lgkm waits). Inner loop = DS + VALU only.
//  Tile 64x * 2y * 8z, both-ic halo: 62.7 + 11 KB -> 2 blocks/CU,
//  1024 blocks = 2 rounds (round-2 compute overlaps round-1 stores).
//  Thread = (lx, ly, zh): one 4-z column; 10 ds_read per 112 FMA.
// ============================================================
#define TZc 8
#define TYc 2
#define LXc (Wn + 6)   /* 70 */
#define LYc (TYc + 6)  /* 8  */
#define LZc (TZc + 6)  /* 14 */
#define HALO1 (LZc * LYc * LXc)  /* 7840 */
#define NW1 (4 * 2 * 7 * 7 * 7)  /* 2744 */

__global__ __launch_bounds__(256) void conv_kernel(
    const float* __restrict__ ca_g,
    const float* __restrict__ s_avg, const float* __restrict__ s_max,
    const float* __restrict__ w1, const float* __restrict__ w2,
    float* __restrict__ out) {
    __shared__ float sIn[2 * HALO1];                  // 62.7 KB
    __shared__ __align__(16) float wlds[NW1];         // 11 KB
    __shared__ float ca_s[Cn];

    const int t = threadIdx.x;
    const int bid = blockIdx.x;
    const int b = bid >> 8;            // 256 tiles per batch
    const int tile = bid & 255;
    const int tz = tile >> 5, ty = tile & 31;  // 8 z-tiles x 32 y-tiles
    const int z0 = tz * TZc, y0 = ty * TYc;

    if (t < Cn) ca_s[t] = ca_g[b * Cn + t];

    // ---- stage reordered weights: wlds[((ic*7+kh)*7+kw)*28 + kd*4 + oc] ----
    for (int i = t; i < NW1; i += 256) {
        const int g = i / 28, r = i - g * 28;
        const int kd = r >> 2, oc = r & 3;
        const int ic = g / 49;
        const int kh = (g / 7) % 7;
        const int kw = g % 7;
        wlds[i] = w1[(((oc * 2 + ic) * 7 + kd) * 7 + kh) * 7 + kw];
    }

    // ---- load both halo buffers ----
    const float* srcA = s_avg + (size_t)b * DHW;
    const float* srcM = s_max + (size_t)b * DHW;
    for (int i = t; i < 2 * HALO1; i += 256) {
        const int ic = i / HALO1;
        const int r0 = i - ic * HALO1;
        const int xx = r0 % LXc;
        const int rem = r0 / LXc;
        const int yy = rem % LYc;
        const int zz = rem / LYc;
        const int gz = z0 + zz - 3, gy = y0 + yy - 3, gx = xx - 3;
        float v = 0.f;
        if ((unsigned)gz < (unsigned)Dn && (unsigned)gy < (unsigned)Hn &&
            (unsigned)gx < (unsigned)Wn)
            v = (ic ? srcM : srcA)[(gz * Hn + gy) * Wn + gx];
        sIn[i] = v;
    }
    __syncthreads();

    // ---- compute: thread (lx, ly, zh) owns 4-z column ----
    const int lx = t & 63, ly = (t >> 6) & 1, zh = t >> 7;

    float a0[4] = {0.f, 0.f, 0.f, 0.f};
    float a1[4] = {0.f, 0.f, 0.f, 0.f};
    float a2[4] = {0.f, 0.f, 0.f, 0.f};
    float a3[4] = {0.f, 0.f, 0.f, 0.f};

#pragma unroll 1
    for (int ic = 0; ic < 2; ++ic)
#pragma unroll 1
        for (int kh = 0; kh < 7; ++kh)
#pragma unroll 1
            for (int kw = 0; kw < 7; ++kw) {
                float incol[10];
                const int ibase =
                    ic * HALO1 + ((zh * 4) * LYc + (ly + kh)) * LXc + (lx + kw);
#pragma unroll
                for (int s = 0; s < 10; ++s)
                    incol[s] = sIn[ibase + s * (LYc * LXc)];
                const f4* wg = reinterpret_cast<const f4*>(
                    wlds + ((ic * 7 + kh) * 7 + kw) * 28);
#pragma unroll
                for (int kd = 0; kd < 7; ++kd) {
                    const f4 wv = wg[kd];  // uniform addr -> broadcast
#pragma unroll
                    for (int o = 0; o < 4; ++o) {
                        const float iv = incol[o + kd];
                        a0[o] += iv * wv.x;
                        a1[o] += iv * wv.y;
                        a2[o] += iv * wv.z;
                        a3[o] += iv * wv.w;
                    }
                }
            }

    const float c20 = w2[0], c21 = w2[1], c22 = w2[2], c23 = w2[3];
    float sv[4];
#pragma unroll
    for (int o = 0; o < 4; ++o) {
        float s = fmaxf(a0[o], 0.f) * c20 + fmaxf(a1[o], 0.f) * c21 +
                  fmaxf(a2[o], 0.f) * c22 + fmaxf(a3[o], 0.f) * c23;
        sv[o] = 1.f / (1.f + expf(-s));
    }

    // ---- NT stores from registers; 256B contiguous per wave-inst ----
    const size_t base = (size_t)b * Cn * DHW +
                        (size_t)(z0 + zh * 4) * HW + (size_t)(y0 + ly) * Wn + lx;
#pragma unroll 1
    for (int c = 0; c < Cn; ++c) {
        const float cav = ca_s[c];
        const size_t cb = base + (size_t)c * DHW;
#pragma unroll
        for (int o = 0; o < 4; ++o) {
            const float a = sv[o] * cav;
            __builtin_nontemporal_store(a, out + cb + o * HW);
            __builtin_nontemporal_store(1.f - a, out + TOT + cb + o * HW);
        }
    }
}

extern "C" void kernel_launch(void* const* d_in, const int* in_sizes, int n_in,
                              void* d_out, int out_size, void* d_ws,
                              size_t ws_size, hipStream_t stream) {
    const float* x = (const float*)d_in[0];
    const float* fc1_w = (const float*)d_in[1];
    const float* fc1_b = (const float*)d_in[2];
    const float* fc2_w = (const float*)d_in[3];
    const float* fc2_b = (const float*)d_in[4];
    const float* conv1_w = (const float*)d_in[5];
    const float* conv2_w = (const float*)d_in[6];

    float* ws = (float*)d_ws;
    float* s_avg = ws;                               // B*DHW
    float* s_max = s_avg + (size_t)Bn * DHW;         // B*DHW
    float* part_sum = s_max + (size_t)Bn * DHW;      // B*C*NCHUNK
    float* part_max = part_sum + Bn * Cn * NCHUNK;   // B*C*NCHUNK
    float* ca = part_max + Bn * Cn * NCHUNK;         // B*C

    reduce_kernel<<<Bn * NCHUNK, 256, 0, stream>>>(x, s_avg, s_max, part_sum,
                                                   part_max);
    ca_kernel<<<1, 256, 0, stream>>>(part_sum, part_max, fc1_w, fc1_b, fc2_w,
                                     fc2_b, ca);
    conv_kernel<<<Bn * 256, 256, 0, stream>>>(ca, s_avg, s_max, conv1_w,
                                              conv2_w, (float*)d_out);
}

// Round 12
// 196.089 us; speedup vs baseline: 1.2753x; 1.2753x over previous
//
#include <hip/hip_runtime.h>
#include <math.h>

#define Bn 4
#define Cn 32
#define Dn 64
#define Hn 64
#define Wn 64
#define HW (Hn * Wn)
#define DHW (Dn * Hn * Wn)      /* 262144 */
#define TOT (Bn * Cn * DHW)     /* 33554432 */
#define NCHUNK 256              /* spatial chunks per batch in reduce */

typedef float f4 __attribute__((ext_vector_type(4)));

// ============================================================
// Kernel 1: fused reductions (atomic-free, fence-free).
// ============================================================
__global__ __launch_bounds__(256, 4) void reduce_kernel(
    const float* __restrict__ x,
    float* __restrict__ s_avg, float* __restrict__ s_max,
    float* __restrict__ part_sum, float* __restrict__ part_max) {
    const int b = blockIdx.x / NCHUNK;
    const int chunk = blockIdx.x % NCHUNK;
    const int base = chunk * 1024 + threadIdx.x * 4;
    const int lane = threadIdx.x & 63;
    const int wid = threadIdx.x >> 6;

    f4 ssum = {0.f, 0.f, 0.f, 0.f};
    f4 smax = {-INFINITY, -INFINITY, -INFINITY, -INFINITY};
    float tsum[Cn], tmax[Cn];

    const float* xp = x + (size_t)b * Cn * DHW + base;
#pragma unroll
    for (int g = 0; g < Cn / 8; ++g) {
        f4 v[8];
#pragma unroll
        for (int j = 0; j < 8; ++j)
            v[j] = *reinterpret_cast<const f4*>(xp + (size_t)(g * 8 + j) * DHW);
#pragma unroll
        for (int j = 0; j < 8; ++j) {
            const int c = g * 8 + j;
            ssum += v[j];
            smax.x = fmaxf(smax.x, v[j].x); smax.y = fmaxf(smax.y, v[j].y);
            smax.z = fmaxf(smax.z, v[j].z); smax.w = fmaxf(smax.w, v[j].w);
            tsum[c] = (v[j].x + v[j].y) + (v[j].z + v[j].w);
            tmax[c] = fmaxf(fmaxf(v[j].x, v[j].y), fmaxf(v[j].z, v[j].w));
        }
    }

    *reinterpret_cast<f4*>(s_avg + (size_t)b * DHW + base) = ssum * (1.f / Cn);
    *reinterpret_cast<f4*>(s_max + (size_t)b * DHW + base) = smax;

    __shared__ float redS[4][Cn];
    __shared__ float redM[4][Cn];
#pragma unroll
    for (int c = 0; c < Cn; ++c) {
        float ps = tsum[c], pm = tmax[c];
#pragma unroll
        for (int off = 32; off; off >>= 1) {
            ps += __shfl_xor(ps, off);
            pm = fmaxf(pm, __shfl_xor(pm, off));
        }
        if (lane == 0) { redS[wid][c] = ps; redM[wid][c] = pm; }
    }
    __syncthreads();
    if (threadIdx.x < Cn) {
        const int c = threadIdx.x;
        float s = (redS[0][c] + redS[1][c]) + (redS[2][c] + redS[3][c]);
        float m = fmaxf(fmaxf(redM[0][c], redM[1][c]),
                        fmaxf(redM[2][c], redM[3][c]));
        part_sum[(b * Cn + c) * NCHUNK + chunk] = s;
        part_max[(b * Cn + c) * NCHUNK + chunk] = m;
    }
}

// ============================================================
// Kernel 2: partial-reduce + channel-attention MLP. 1 block, 256 threads.
// ============================================================
__global__ __launch_bounds__(256) void ca_kernel(
    const float* __restrict__ part_sum, const float* __restrict__ part_max,
    const float* __restrict__ fc1_w, const float* __restrict__ fc1_b,
    const float* __restrict__ fc2_w, const float* __restrict__ fc2_b,
    float* __restrict__ ca) {
    __shared__ float inpAll[Bn][64];
    __shared__ float h[128];
    const int t = threadIdx.x;
    {
        const int which = t >> 7;        // 0: sum, 1: max
        const int b = (t >> 5) & 3;
        const int c = t & 31;
        const f4* p4 = reinterpret_cast<const f4*>(
            (which ? part_max : part_sum) + (b * Cn + c) * NCHUNK);
        if (which == 0) {
            float acc = 0.f;
#pragma unroll
            for (int i = 0; i < NCHUNK / 4; ++i) {
                f4 v = p4[i];
                acc += (v.x + v.y) + (v.z + v.w);
            }
            inpAll[b][c] = acc * (1.f / DHW);
        } else {
            float m = -INFINITY;
#pragma unroll
            for (int i = 0; i < NCHUNK / 4; ++i) {
                f4 v = p4[i];
                m = fmaxf(m, fmaxf(fmaxf(v.x, v.y), fmaxf(v.z, v.w)));
            }
            inpAll[b][Cn + c] = m;
        }
    }
    __syncthreads();
#pragma unroll 1
    for (int b = 0; b < Bn; ++b) {
        if (t < 128) {
            float acc = fc1_b[t];
#pragma unroll
            for (int k = 0; k < 64; ++k) acc += fc1_w[t * 64 + k] * inpAll[b][k];
            h[t] = fmaxf(acc, 0.f);
        }
        __syncthreads();
        if (t < Cn) {
            float a2 = fc2_b[t];
#pragma unroll
            for (int k = 0; k < 128; ++k) a2 += fc2_w[t * 128 + k] * h[k];
            ca[b * Cn + t] = 1.f / (1.f + expf(-a2));
        }
        __syncthreads();
    }
}

// ============================================================
// Kernel 3: conv + epilogue, x-in-registers formulation.
//  Tile 32x * 4y * 16z, both ic halos in LDS (70.4 KB -> 2 blocks/CU).
//  Thread = (xq, ly, zh): 4-aligned-x quad x 2 z = 8 outputs x 4 oc.
//  Per (ic,kh,kd): 12-float x-window via 3 ds_read_b128 (z-sliding, 2-row
//  register window, parity-indexed); all 7 kw taps from registers.
//  Weights: wave-uniform s_load (scalar pipe — R11 lesson: LDS weights
//  choke the DS pipe; R10 lesson: keep DS inst count per FMA tiny).
//  DS: 336 b128/wave per 44K VALU cyc (~9%). Stores: 128 dwordx4 NT.
// ============================================================
#define TXc 32
#define TYc 4
#define TZc 16
#define LXc 40   /* 38 used, padded to 40 for 16B row alignment */
#define LYc (TYc + 6)   /* 10 */
#define LZc (TZc + 6)   /* 22 */
#define HALO1 (LZc * LYc * LXc)  /* 8800 */

__global__ __launch_bounds__(256) void conv_kernel(
    const float* __restrict__ ca_g,
    const float* __restrict__ s_avg, const float* __restrict__ s_max,
    const float* __restrict__ w1, const float* __restrict__ w2,
    float* __restrict__ out) {
    __shared__ __align__(16) float sIn[2 * HALO1];   // 70.4 KB
    __shared__ float ca_s[Cn];

    const int t = threadIdx.x;
    const int bid = blockIdx.x;
    const int b = bid >> 7;            // 128 tiles per batch
    const int tile = bid & 127;
    const int txi = tile & 1, tyi = (tile >> 1) & 15, tzi = tile >> 5;
    const int x0 = txi * TXc, y0 = tyi * TYc, z0 = tzi * TZc;

    if (t < Cn) ca_s[t] = ca_g[b * Cn + t];

    // ---- stage both halo buffers ----
    const float* srcA = s_avg + (size_t)b * DHW;
    const float* srcM = s_max + (size_t)b * DHW;
    for (int i = t; i < 2 * HALO1; i += 256) {
        const int ic = i / HALO1;
        const int r = i - ic * HALO1;
        const int zz = r / (LYc * LXc);
        const int r2 = r - zz * (LYc * LXc);
        const int yy = r2 / LXc;
        const int xx = r2 - yy * LXc;
        const int gz = z0 + zz - 3, gy = y0 + yy - 3, gx = x0 + xx - 3;
        float v = 0.f;
        if ((unsigned)gz < (unsigned)Dn && (unsigned)gy < (unsigned)Hn &&
            (unsigned)gx < (unsigned)Wn)
            v = (ic ? srcM : srcA)[(gz * Hn + gy) * Wn + gx];
        sIn[i] = v;
    }
    __syncthreads();

    // ---- compute ----
    const int xq = t & 7, ly = (t >> 3) & 3, zh = t >> 5;  // zh in [0,8)
    const int xb = xq * 4;  // halo-x base, 16B aligned

    float acc[4][2][4];  // [oc][z2][j]
#pragma unroll
    for (int oc = 0; oc < 4; ++oc)
#pragma unroll
        for (int z2 = 0; z2 < 2; ++z2)
#pragma unroll
            for (int j = 0; j < 4; ++j) acc[oc][z2][j] = 0.f;

#pragma unroll 1
    for (int ic = 0; ic < 2; ++ic)
#pragma unroll 1
        for (int kh = 0; kh < 7; ++kh) {
            const int rowoff = ic * HALO1 + (ly + kh) * LXc + xb;
            float win[2][12];
            {   // preload z-row (2zh) into win[0]
                const f4* rp = reinterpret_cast<const f4*>(
                    sIn + rowoff + (2 * zh) * (LYc * LXc));
                const f4 r0 = rp[0], r1 = rp[1], r2 = rp[2];
                win[0][0] = r0.x; win[0][1] = r0.y; win[0][2] = r0.z; win[0][3] = r0.w;
                win[0][4] = r1.x; win[0][5] = r1.y; win[0][6] = r1.z; win[0][7] = r1.w;
                win[0][8] = r2.x; win[0][9] = r2.y; win[0][10] = r2.z; win[0][11] = r2.w;
            }
#pragma unroll
            for (int kd = 0; kd < 7; ++kd) {
                float* wa = win[kd & 1];         // row 2zh+kd   (out z2=0)
                float* wb = win[(kd + 1) & 1];   // row 2zh+kd+1 (out z2=1)
                {   // load row (2zh+kd+1) into wb
                    const f4* rp = reinterpret_cast<const f4*>(
                        sIn + rowoff + (2 * zh + kd + 1) * (LYc * LXc));
                    const f4 r0 = rp[0], r1 = rp[1], r2 = rp[2];
                    wb[0] = r0.x; wb[1] = r0.y; wb[2] = r0.z; wb[3] = r0.w;
                    wb[4] = r1.x; wb[5] = r1.y; wb[6] = r1.z; wb[7] = r1.w;
                    wb[8] = r2.x; wb[9] = r2.y; wb[10] = r2.z; wb[11] = r2.w;
                }
                const float* wp = w1 + ic * 343 + kd * 49 + kh * 7;
#pragma unroll
                for (int kw = 0; kw < 7; ++kw)
#pragma unroll
                    for (int oc = 0; oc < 4; ++oc) {
                        // wave-uniform address -> scalar load
                        const float wv = wp[oc * 686 + kw];
#pragma unroll
                        for (int j = 0; j < 4; ++j) {
                            acc[oc][0][j] += wa[j + kw] * wv;
                            acc[oc][1][j] += wb[j + kw] * wv;
                        }
                    }
            }
        }

    // ---- 1x1 conv + sigmoid ----
    const float c20 = w2[0], c21 = w2[1], c22 = w2[2], c23 = w2[3];
    f4 sv[2];
#pragma unroll
    for (int z2 = 0; z2 < 2; ++z2)
#pragma unroll
        for (int j = 0; j < 4; ++j) {
            float s = fmaxf(acc[0][z2][j], 0.f) * c20 +
                      fmaxf(acc[1][z2][j], 0.f) * c21 +
                      fmaxf(acc[2][z2][j], 0.f) * c22 +
                      fmaxf(acc[3][z2][j], 0.f) * c23;
            sv[z2][j] = 1.f / (1.f + expf(-s));
        }

    // ---- NT f4 stores from registers ----
    const size_t base0 = (size_t)b * Cn * DHW + (size_t)(z0 + 2 * zh) * HW +
                         (size_t)(y0 + ly) * Wn + (x0 + xb);
    f4* outp = reinterpret_cast<f4*>(out);
#pragma unroll 1
    for (int c = 0; c < Cn; ++c) {
        const float cav = ca_s[c];
        const size_t cb4 = (base0 + (size_t)c * DHW) >> 2;
#pragma unroll
        for (int z2 = 0; z2 < 2; ++z2) {
            const f4 a = sv[z2] * cav;
            const f4 an = 1.f - a;
            __builtin_nontemporal_store(a, outp + cb4 + z2 * (HW / 4));
            __builtin_nontemporal_store(an, outp + (TOT / 4) + cb4 + z2 * (HW / 4));
        }
    }
}

extern "C" void kernel_launch(void* const* d_in, const int* in_sizes, int n_in,
                              void* d_out, int out_size, void* d_ws,
                              size_t ws_size, hipStream_t stream) {
    const float* x = (const float*)d_in[0];
    const float* fc1_w = (const float*)d_in[1];
    const float* fc1_b = (const float*)d_in[2];
    const float* fc2_w = (const float*)d_in[3];
    const float* fc2_b = (const float*)d_in[4];
    const float* conv1_w = (const float*)d_in[5];
    const float* conv2_w = (const float*)d_in[6];

    float* ws = (float*)d_ws;
    float* s_avg = ws;                               // B*DHW
    float* s_max = s_avg + (size_t)Bn * DHW;         // B*DHW
    float* part_sum = s_max + (size_t)Bn * DHW;      // B*C*NCHUNK
    float* part_max = part_sum + Bn * Cn * NCHUNK;   // B*C*NCHUNK
    float* ca = part_max + Bn * Cn * NCHUNK;         // B*C

    reduce_kernel<<<Bn * NCHUNK, 256, 0, stream>>>(x, s_avg, s_max, part_sum,
                                                   part_max);
    ca_kernel<<<1, 256, 0, stream>>>(part_sum, part_max, fc1_w, fc1_b, fc2_w,
                                     fc2_b, ca);
    conv_kernel<<<Bn * 128, 256, 0, stream>>>(ca, s_avg, s_max, conv1_w,
                                              conv2_w, (float*)d_out);
}